// Round 13
// baseline (3392.147 us; speedup 1.0000x reference)
//
#include <hip/hip_runtime.h>
#include <hip/hip_bf16.h>

#define NPTS   16384
#define PPC    2048
#define DINF   128
#define KNB    32
#define HID    256
#define DOUTF  256

static __device__ __forceinline__ unsigned short bf16bits(float f) {
    __hip_bfloat16 h = __float2bfloat16(f);
    return *reinterpret_cast<unsigned short*>(&h);
}

// ---------------------------------------------------------------------------
// FUSED kernel: ball query + gather + 2-layer MLP + masked max.
// One block = one wave = one point. fp32 in, fp32 out.
//
// R13 theory: ref = np.einsum('bik,bjk->bij') (optimize=False). For k=3,
// numpy's einsum skips the unrolled-by-8 main loop and runs the
// finish_after_unrolled_loop FALLTHROUGH SWITCH, which accumulates in
// DESCENDING index order: accum = z*z'; accum += y*y'; accum += x*x' —
// scalar SSE2 (baseline x86-64 wheel, no FMA). So ref dot =
// (z*z' + y*y') + x*x', no FMA. I tried ascending-noFMA (R7),
// fp64 (R8), ascending-FMA (R12) — all bit-identical 0.95 because the one
// ref-flipped pair is insensitive to MY rounding; only reproducing REF's
// exact chain makes membership bit-identical. n2 via np pairwise-reduce
// (len 3 -> sequential ascending, = mine); outer (n2i+n2j)-2*dot; 0.04f, <=.
// Single change vs R7: dot accumulation order reversed.
// ---------------------------------------------------------------------------
#define MSG_STRIDE 168   // halves; row = slot; 131 used, zero-padded to 160
#define H_STRIDE   264   // halves; row = slot; 256 used

__global__ __launch_bounds__(64, 1) void fused_kernel(
    const float* __restrict__ x,   const float* __restrict__ pos,
    const float* __restrict__ W1,  const float* __restrict__ b1,
    const float* __restrict__ W2,  const float* __restrict__ b2,
    float* __restrict__ out)
{
    __shared__ __align__(16) unsigned short msg[32 * MSG_STRIDE];  // 10.5 KB
    __shared__ __align__(16) unsigned short hsh[32 * H_STRIDE];    // 16.5 KB
    __shared__ int nbr[KNB];

    const int lane  = threadIdx.x;
    const int point = blockIdx.x;
    const int cb    = point & ~(PPC - 1);

    // ---- ball query: first 32 ascending-j with d2 <= 0.04f ----
    const float pix = pos[(size_t)point * 3 + 0];
    const float piy = pos[(size_t)point * 3 + 1];
    const float piz = pos[(size_t)point * 3 + 2];
    // n2: multiply then sequential ascending add (np.sum pairwise, len3)
    const float n2i = __fadd_rn(__fadd_rn(__fmul_rn(pix, pix), __fmul_rn(piy, piy)),
                                __fmul_rn(piz, piz));
    int k = 0;
    for (int t = 0; t < PPC / 64 && k < KNB; ++t) {
        const int j = t * 64 + lane;
        const float pjx = pos[(size_t)(cb + j) * 3 + 0];
        const float pjy = pos[(size_t)(cb + j) * 3 + 1];
        const float pjz = pos[(size_t)(cb + j) * 3 + 2];
        const float n2j = __fadd_rn(__fadd_rn(__fmul_rn(pjx, pjx), __fmul_rn(pjy, pjy)),
                                    __fmul_rn(pjz, pjz));
        // R13: numpy einsum k=3 epilogue — DESCENDING accumulation, no FMA:
        //   accum  = z*z'; accum += y*y'; accum += x*x'
        const float dot = __fadd_rn(__fadd_rn(__fmul_rn(piz, pjz), __fmul_rn(piy, pjy)),
                                    __fmul_rn(pix, pjx));
        const float d2  = __fsub_rn(__fadd_rn(n2i, n2j), __fmul_rn(2.0f, dot));
        const bool in   = (d2 <= 0.04f);
        const unsigned long long m = __ballot(in);
        if (in) {
            const int slot = k + (int)__popcll(m & ((1ull << lane) - 1ull));
            if (slot < KNB) nbr[slot] = j;
        }
        k += (int)__popcll(m);
    }
    const int myc = (k < KNB) ? k : KNB;            // = min(#within, 32)
    if (lane >= myc && lane < KNB) nbr[lane] = 0;   // pad: any valid j (masked)
    __syncthreads();

    // ---- gather: msg[slot][0..127] = bf16(x_j), [128..130] = rel, rest 0 ----
    #pragma unroll
    for (int it = 0; it < 8; ++it) {
        const int task = it * 64 + lane;            // 0..511
        const int r    = task >> 4;                 // slot 0..31
        const int sg   = task & 15;                 // 8-float segment
        const int j    = nbr[r];
        const float* xf = x + (size_t)(cb + j) * DINF + sg * 8;
        const float4 pa = reinterpret_cast<const float4*>(xf)[0];
        const float4 pb = reinterpret_cast<const float4*>(xf)[1];
        uint4 v;
        v.x = (unsigned int)bf16bits(pa.x) | ((unsigned int)bf16bits(pa.y) << 16);
        v.y = (unsigned int)bf16bits(pa.z) | ((unsigned int)bf16bits(pa.w) << 16);
        v.z = (unsigned int)bf16bits(pb.x) | ((unsigned int)bf16bits(pb.y) << 16);
        v.w = (unsigned int)bf16bits(pb.z) | ((unsigned int)bf16bits(pb.w) << 16);
        *reinterpret_cast<uint4*>(&msg[r * MSG_STRIDE + sg * 8]) = v;
    }
    if (lane < KNB) {
        const int j = nbr[lane];
        const float rx = pos[(size_t)(cb + j) * 3 + 0] - pix;
        const float ry = pos[(size_t)(cb + j) * 3 + 1] - piy;
        const float rz = pos[(size_t)(cb + j) * 3 + 2] - piz;
        uint4 vr;
        vr.x = (unsigned int)bf16bits(rx) | ((unsigned int)bf16bits(ry) << 16);
        vr.y = (unsigned int)bf16bits(rz);
        vr.z = 0u; vr.w = 0u;
        const uint4 z = make_uint4(0u, 0u, 0u, 0u);
        *reinterpret_cast<uint4*>(&msg[lane * MSG_STRIDE + 128]) = vr;
        *reinterpret_cast<uint4*>(&msg[lane * MSG_STRIDE + 136]) = z;
        *reinterpret_cast<uint4*>(&msg[lane * MSG_STRIDE + 144]) = z;
        *reinterpret_cast<uint4*>(&msg[lane * MSG_STRIDE + 152]) = z;
        *reinterpret_cast<uint4*>(&msg[lane * MSG_STRIDE + 160]) = z;
    }
    __syncthreads();

    // ---- layer 1: lane owns cols {lane + 64b} ----
    float hacc[32][4];
    #pragma unroll
    for (int s = 0; s < 32; ++s)
        #pragma unroll
        for (int b = 0; b < 4; ++b) hacc[s][b] = 0.f;

    for (int kp = 0; kp < 66; ++kp) {
        const int kk = kp * 2;
        float wa[4], wb[4];
        #pragma unroll
        for (int b = 0; b < 4; ++b) wa[b] = W1[(size_t)kk * HID + lane + 64 * b];
        const bool hasb = (kk + 1) < 131;
        #pragma unroll
        for (int b = 0; b < 4; ++b) wb[b] = hasb ? W1[(size_t)(kk + 1) * HID + lane + 64 * b] : 0.f;
        #pragma unroll
        for (int s = 0; s < 32; ++s) {
            const unsigned int mw = *reinterpret_cast<const unsigned int*>(&msg[s * MSG_STRIDE + kk]);
            union { unsigned int u; float f; } lo, hi;
            lo.u = mw << 16; hi.u = mw & 0xFFFF0000u;
            #pragma unroll
            for (int b = 0; b < 4; ++b) hacc[s][b] += lo.f * wa[b] + hi.f * wb[b];
        }
    }
    {
        float bb[4];
        #pragma unroll
        for (int b = 0; b < 4; ++b) bb[b] = b1[lane + 64 * b];
        #pragma unroll
        for (int s = 0; s < 32; ++s)
            #pragma unroll
            for (int b = 0; b < 4; ++b)
                hsh[s * H_STRIDE + lane + 64 * b] = bf16bits(fmaxf(hacc[s][b] + bb[b], 0.f));
    }
    __syncthreads();

    // ---- layer 2 ----
    float oacc[32][4];
    #pragma unroll
    for (int s = 0; s < 32; ++s)
        #pragma unroll
        for (int b = 0; b < 4; ++b) oacc[s][b] = 0.f;

    for (int kp = 0; kp < 128; ++kp) {
        const int kk = kp * 2;
        float wa[4], wb[4];
        #pragma unroll
        for (int b = 0; b < 4; ++b) wa[b] = W2[(size_t)kk * DOUTF + lane + 64 * b];
        #pragma unroll
        for (int b = 0; b < 4; ++b) wb[b] = W2[(size_t)(kk + 1) * DOUTF + lane + 64 * b];
        #pragma unroll
        for (int s = 0; s < 32; ++s) {
            const unsigned int hw = *reinterpret_cast<const unsigned int*>(&hsh[s * H_STRIDE + kk]);
            union { unsigned int u; float f; } lo, hi;
            lo.u = hw << 16; hi.u = hw & 0xFFFF0000u;
            #pragma unroll
            for (int b = 0; b < 4; ++b) oacc[s][b] += lo.f * wa[b] + hi.f * wb[b];
        }
    }

    // ---- epilogue: bias + relu + count-masked max; fp32 store ----
    float b2v[4], m[4];
    #pragma unroll
    for (int b = 0; b < 4; ++b) { b2v[b] = b2[lane + 64 * b]; m[b] = 0.f; }
    #pragma unroll
    for (int s = 0; s < 32; ++s) {
        if (s < myc) {
            #pragma unroll
            for (int b = 0; b < 4; ++b)
                m[b] = fmaxf(m[b], fmaxf(oacc[s][b] + b2v[b], 0.f));
        }
    }
    #pragma unroll
    for (int b = 0; b < 4; ++b)
        out[(size_t)point * DOUTF + lane + 64 * b] = m[b];
}

// ---------------------------------------------------------------------------
// tail: pos passthrough (fp32 exact) + batch = i>>11 as fp32.
// ---------------------------------------------------------------------------
__global__ __launch_bounds__(256) void tail_kernel(
    const float* __restrict__ pos,
    float* __restrict__ outpos,
    float* __restrict__ outbat)
{
    const int gid = blockIdx.x * 256 + threadIdx.x;
    if (gid < NPTS * 3) {
        outpos[gid] = pos[gid];
    } else {
        const int i = gid - NPTS * 3;
        if (i < NPTS) outbat[i] = (float)(i >> 11);
    }
}

extern "C" void kernel_launch(void* const* d_in, const int* in_sizes, int n_in,
                              void* d_out, int out_size, void* d_ws, size_t ws_size,
                              hipStream_t stream)
{
    // remap inputs by element-count fingerprint (R5 diag proved these sizes)
    const float *x = nullptr, *pos = nullptr, *W1 = nullptr, *W2 = nullptr;
    const float *b1 = nullptr, *b2 = nullptr;
    int nbias = 0;
    for (int i = 0; i < n_in && i < 16; ++i) {
        switch (in_sizes[i]) {
            case NPTS * DINF: x   = (const float*)d_in[i]; break;
            case NPTS * 3:    pos = (const float*)d_in[i]; break;
            case 131 * HID:   W1  = (const float*)d_in[i]; break;
            case HID * DOUTF: W2  = (const float*)d_in[i]; break;
            case 256:         if (nbias == 0) b1 = (const float*)d_in[i];
                              else            b2 = (const float*)d_in[i];
                              ++nbias; break;
            default: break;   // batch (unused; structurally i>>11)
        }
    }
    if (!x)   x   = (const float*)d_in[0];
    if (!pos) pos = (const float*)d_in[1];
    if (!W1)  W1  = (const float*)d_in[3];
    if (!b1)  b1  = (const float*)d_in[4];
    if (!W2)  W2  = (const float*)d_in[5];
    if (!b2)  b2  = (const float*)d_in[6];

    // fp32 output layout: out[N*256] | pos[N*3] | batch[N]
    float* out    = (float*)d_out;
    float* outpos = out + (size_t)NPTS * DOUTF;
    float* outbat = outpos + (size_t)NPTS * 3;

    hipLaunchKernelGGL(fused_kernel, dim3(NPTS), dim3(64), 0, stream,
                       x, pos, W1, b1, W2, b2, out);
    if (out_size >= NPTS * DOUTF + NPTS * 3 + NPTS) {
        hipLaunchKernelGGL(tail_kernel, dim3(256), dim3(256), 0, stream,
                           pos, outpos, outbat);
    }
}

// Round 14
// 316.186 us; speedup vs baseline: 10.7283x; 10.7283x over previous
//
#include <hip/hip_runtime.h>
#include <hip/hip_bf16.h>

#define NPTS   16384
#define PPC    2048
#define DINF   128
#define KNB    32
#define HID    256
#define DOUTF  256

typedef __bf16 bf16x8 __attribute__((ext_vector_type(8)));
typedef float  f32x4  __attribute__((ext_vector_type(4)));

// ---- ws layout (bytes) ----
// [0,       1048576) : neighbor idx  ushort [NPTS][32]  (cloud-local j)
// [1048576, 1064960) : neighbor cnt  uchar  [NPTS]
// [1064960, 1146880) : W1 swizzled   bf16   [5][16][64][8]
// [1146880, 1277952) : W2 swizzled   bf16   [8][16][64][8]

static __device__ __forceinline__ unsigned short bf16bits(float f) {
    __hip_bfloat16 h = __float2bfloat16(f);
    return *reinterpret_cast<unsigned short*>(&h);
}

// ---------------------------------------------------------------------------
// Kernel 1: ball query, 64 points/block, cloud cached in LDS.
// d2 semantics VALIDATED in R13: n2 = (x^2+y^2)+z^2 ascending;
// dot = (z*z'+y*y')+x*x' DESCENDING (numpy einsum k=3 epilogue); no FMA;
// d2 = (n2i+n2j) - 2*dot; d2 <= 0.04f; first-32-ascending-index.
// ---------------------------------------------------------------------------
__global__ __launch_bounds__(256) void neigh_kernel(
    const float* __restrict__ pos,
    unsigned short* __restrict__ idx,
    unsigned char* __restrict__ cnt)
{
    __shared__ __align__(16) float4 sp[PPC];         // 32 KB: x,y,z,n2
    __shared__ unsigned short lists[4][64][KNB];     // 16 KB
    __shared__ unsigned char  scnt[4][64];

    const int tid = threadIdx.x;
    const int p0  = blockIdx.x * 64;
    const int cb  = (p0 / PPC) * PPC;

    for (int t = tid; t < PPC; t += 256) {
        const float x = pos[(size_t)(cb + t) * 3 + 0];
        const float y = pos[(size_t)(cb + t) * 3 + 1];
        const float z = pos[(size_t)(cb + t) * 3 + 2];
        const float n2 = __fadd_rn(__fadd_rn(__fmul_rn(x, x), __fmul_rn(y, y)), __fmul_rn(z, z));
        sp[t] = make_float4(x, y, z, n2);
    }
    __syncthreads();

    const int seg = tid >> 6;                        // wave-uniform
    const int p   = tid & 63;
    const float4 pi = sp[p0 - cb + p];

    int c = 0;
    const int jb = seg * (PPC / 4);
    for (int jj = 0; jj < PPC / 4; ++jj) {
        const int j = jb + jj;
        const float4 pj = sp[j];                     // uniform: LDS broadcast
        const float dot = __fadd_rn(__fadd_rn(__fmul_rn(pi.z, pj.z), __fmul_rn(pi.y, pj.y)),
                                    __fmul_rn(pi.x, pj.x));     // descending (validated)
        const float d2  = __fsub_rn(__fadd_rn(pi.w, pj.w), __fmul_rn(2.0f, dot));
        if (d2 <= 0.04f && c < KNB) { lists[seg][p][c] = (unsigned short)j; ++c; }
    }
    scnt[seg][p] = (unsigned char)c;
    __syncthreads();

    if (tid < 64) {
        const int point = p0 + tid;
        unsigned short* op = idx + (size_t)point * KNB;
        int k = 0;
        for (int s = 0; s < 4; ++s) {                // ascending-j segment order
            const int cc = scnt[s][tid];
            for (int r = 0; r < cc && k < KNB; ++r) op[k++] = lists[s][tid][r];
        }
        cnt[point] = (unsigned char)k;
        for (; k < KNB; ++k) op[k] = 0;              // safe gather idx (masked)
    }
}

// ---------------------------------------------------------------------------
// Kernel 2: swizzle fp32 W1/W2 -> bf16 MFMA B-fragment-major:
//   frag[(kstep*16+nt)*64+lane][j] = bf16(W[kstep*32+(lane>>4)*8+j][nt*16+(lane&15)])
// W1 K padded 131 -> 160 with zeros. One dwordx4 per B-fragment per lane.
// ---------------------------------------------------------------------------
__global__ __launch_bounds__(256) void prep_kernel(
    const float* __restrict__ W1, const float* __restrict__ W2,
    unsigned short* __restrict__ w1s, unsigned short* __restrict__ w2s)
{
    const int gid = blockIdx.x * 256 + threadIdx.x;
    if (gid < 5 * 1024) {
        const int ks = gid >> 10, rem = gid & 1023, nt = rem >> 6, lane = rem & 63;
        const int n  = nt * 16 + (lane & 15);
        const int k0 = ks * 32 + ((lane >> 4) * 8);
        unsigned int u[4];
        #pragma unroll
        for (int q = 0; q < 4; ++q) {
            const int ka = k0 + 2 * q, kb = ka + 1;
            const unsigned int lo = (ka < 131) ? (unsigned int)bf16bits(W1[(size_t)ka * HID + n]) : 0u;
            const unsigned int hi = (kb < 131) ? (unsigned int)bf16bits(W1[(size_t)kb * HID + n]) : 0u;
            u[q] = lo | (hi << 16);
        }
        reinterpret_cast<uint4*>(w1s)[gid] = make_uint4(u[0], u[1], u[2], u[3]);
    } else if (gid < 5 * 1024 + 8 * 1024) {
        const int t  = gid - 5 * 1024;
        const int ks = t >> 10, rem = t & 1023, nt = rem >> 6, lane = rem & 63;
        const int n  = nt * 16 + (lane & 15);
        const int k0 = ks * 32 + ((lane >> 4) * 8);
        unsigned int u[4];
        #pragma unroll
        for (int q = 0; q < 4; ++q) {
            const unsigned int lo = (unsigned int)bf16bits(W2[(size_t)(k0 + 2 * q) * DOUTF + n]);
            const unsigned int hi = (unsigned int)bf16bits(W2[(size_t)(k0 + 2 * q + 1) * DOUTF + n]);
            u[q] = lo | (hi << 16);
        }
        reinterpret_cast<uint4*>(w2s)[t] = make_uint4(u[0], u[1], u[2], u[3]);
    }
}

// ---------------------------------------------------------------------------
// Kernel 3: tuple tail, fp32: pos passthrough + batch = i>>11.
// ---------------------------------------------------------------------------
__global__ __launch_bounds__(256) void tail_kernel(
    const float* __restrict__ pos,
    float* __restrict__ outpos,
    float* __restrict__ outbat)
{
    const int gid = blockIdx.x * 256 + threadIdx.x;
    if (gid < NPTS * 3) {
        outpos[gid] = pos[gid];
    } else {
        const int i = gid - NPTS * 3;
        if (i < NPTS) outbat[i] = (float)(i >> 11);
    }
}

// ---------------------------------------------------------------------------
// Kernel 4: MFMA gather + MLP + masked max. 1 block = 4 points = 4 waves.
// Per wave: M=32 neighbor rows (2 Mtiles), 8 chunks of 32 h-cols:
//   layer1 (5 Ksteps x 2Mx2N MFMA) -> bias/relu/bf16 -> LDS scratch (C->A)
//   layer2 accumulates acc2[2][16] over 16 out-Ntiles. fp32 epilogue.
// A-frag: A[m=lane&15][k=quad*8+j]; C/D: col=lane&15,row=quad*4+reg (m89).
// Barriers around the scratch round-trip (uniform loop, all waves reach).
// ---------------------------------------------------------------------------
#define MSG_STRIDE 168   // halves: 131 used, pad to 160; 336B rows (16B-align)
#define SCR_STRIDE 40

__global__ __launch_bounds__(256, 2) void sa_kernel(
    const float* __restrict__ x,
    const float* __restrict__ pos,
    const unsigned short* __restrict__ idx,
    const unsigned char*  __restrict__ cnt,
    const unsigned short* __restrict__ w1s,
    const unsigned short* __restrict__ w2s,
    const float* __restrict__ b1,
    const float* __restrict__ b2,
    float* __restrict__ out)
{
    __shared__ __align__(16) unsigned short msg[128 * MSG_STRIDE];  // 42 KB
    __shared__ __align__(16) __bf16 scr[4][32 * SCR_STRIDE];        // 10 KB

    const int tid   = threadIdx.x;
    const int pbase = blockIdx.x * 4;
    const int cb    = (pbase >> 11) << 11;          // all 4 points same cloud

    // ---- gather: msg[row=wave*32+slot][0..127]=bf16(x_j), [128..130]=rel, rest 0
    #pragma unroll
    for (int it = 0; it < 8; ++it) {
        const int task  = it * 256 + tid;           // 0..2047
        const int r     = task >> 4;                // row 0..127
        const int sg    = task & 15;                // 8-float segment
        const int point = pbase + (r >> 5);
        const int slot  = r & 31;
        const int j     = idx[point * KNB + slot];
        const float* xf = x + (size_t)(cb + j) * DINF + sg * 8;
        const float4 pa = reinterpret_cast<const float4*>(xf)[0];
        const float4 pb = reinterpret_cast<const float4*>(xf)[1];
        uint4 v;
        v.x = (unsigned int)bf16bits(pa.x) | ((unsigned int)bf16bits(pa.y) << 16);
        v.y = (unsigned int)bf16bits(pa.z) | ((unsigned int)bf16bits(pa.w) << 16);
        v.z = (unsigned int)bf16bits(pb.x) | ((unsigned int)bf16bits(pb.y) << 16);
        v.w = (unsigned int)bf16bits(pb.z) | ((unsigned int)bf16bits(pb.w) << 16);
        *reinterpret_cast<uint4*>(&msg[r * MSG_STRIDE + sg * 8]) = v;
    }
    if (tid < 128) {
        const int r     = tid;
        const int point = pbase + (r >> 5);
        const int slot  = r & 31;
        const int j     = idx[point * KNB + slot];
        const float rx = x[0] * 0.f + (pos[(size_t)(cb + j) * 3 + 0] - pos[(size_t)point * 3 + 0]);
        const float ry = pos[(size_t)(cb + j) * 3 + 1] - pos[(size_t)point * 3 + 1];
        const float rz = pos[(size_t)(cb + j) * 3 + 2] - pos[(size_t)point * 3 + 2];
        uint4 vr;
        vr.x = (unsigned int)bf16bits(rx) | ((unsigned int)bf16bits(ry) << 16);
        vr.y = (unsigned int)bf16bits(rz);
        vr.z = 0u; vr.w = 0u;
        const uint4 z = make_uint4(0u, 0u, 0u, 0u);
        *reinterpret_cast<uint4*>(&msg[r * MSG_STRIDE + 128]) = vr;
        *reinterpret_cast<uint4*>(&msg[r * MSG_STRIDE + 136]) = z;
        *reinterpret_cast<uint4*>(&msg[r * MSG_STRIDE + 144]) = z;
        *reinterpret_cast<uint4*>(&msg[r * MSG_STRIDE + 152]) = z;
        *reinterpret_cast<uint4*>(&msg[r * MSG_STRIDE + 160]) = z;
    }
    __syncthreads();

    const int w    = tid >> 6;
    const int lane = tid & 63;
    const int quad = lane >> 4;
    const int l15  = lane & 15;
    const int point = pbase + w;
    int myc = cnt[point]; if (myc > KNB) myc = KNB;
    const unsigned short* msgw = &msg[w * 32 * MSG_STRIDE];
    __bf16* scw = scr[w];

    f32x4 acc2[2][16];
    const f32x4 fz = {0.f, 0.f, 0.f, 0.f};
    #pragma unroll
    for (int mt = 0; mt < 2; ++mt)
        #pragma unroll
        for (int nt = 0; nt < 16; ++nt) acc2[mt][nt] = fz;

    for (int hc = 0; hc < 8; ++hc) {
        f32x4 a10 = fz, a11 = fz, a12 = fz, a13 = fz;
        #pragma unroll
        for (int ks = 0; ks < 5; ++ks) {
            const bf16x8 a0  = *reinterpret_cast<const bf16x8*>(msgw + l15 * MSG_STRIDE + ks * 32 + quad * 8);
            const bf16x8 a1  = *reinterpret_cast<const bf16x8*>(msgw + (16 + l15) * MSG_STRIDE + ks * 32 + quad * 8);
            const bf16x8 w0  = *reinterpret_cast<const bf16x8*>(w1s + (size_t)((ks * 16 + hc * 2 + 0) * 64 + lane) * 8);
            const bf16x8 w1v = *reinterpret_cast<const bf16x8*>(w1s + (size_t)((ks * 16 + hc * 2 + 1) * 64 + lane) * 8);
            a10 = __builtin_amdgcn_mfma_f32_16x16x32_bf16(a0, w0,  a10, 0, 0, 0);
            a11 = __builtin_amdgcn_mfma_f32_16x16x32_bf16(a0, w1v, a11, 0, 0, 0);
            a12 = __builtin_amdgcn_mfma_f32_16x16x32_bf16(a1, w0,  a12, 0, 0, 0);
            a13 = __builtin_amdgcn_mfma_f32_16x16x32_bf16(a1, w1v, a13, 0, 0, 0);
        }
        const float bb0 = b1[hc * 32 + l15];
        const float bb1 = b1[hc * 32 + 16 + l15];
        #pragma unroll
        for (int rg = 0; rg < 4; ++rg) {
            const int row0 = quad * 4 + rg;
            scw[row0 * SCR_STRIDE + l15]             = (__bf16)fmaxf(a10[rg] + bb0, 0.f);
            scw[row0 * SCR_STRIDE + 16 + l15]        = (__bf16)fmaxf(a11[rg] + bb1, 0.f);
            scw[(16 + row0) * SCR_STRIDE + l15]      = (__bf16)fmaxf(a12[rg] + bb0, 0.f);
            scw[(16 + row0) * SCR_STRIDE + 16 + l15] = (__bf16)fmaxf(a13[rg] + bb1, 0.f);
        }
        __syncthreads();   // scratch writes -> A-fragment reads
        const bf16x8 h0 = *reinterpret_cast<const bf16x8*>(scw + l15 * SCR_STRIDE + quad * 8);
        const bf16x8 h1 = *reinterpret_cast<const bf16x8*>(scw + (16 + l15) * SCR_STRIDE + quad * 8);
        __syncthreads();   // A-fragment reads -> next iteration's writes
        #pragma unroll
        for (int nt = 0; nt < 16; ++nt) {
            const bf16x8 wv = *reinterpret_cast<const bf16x8*>(w2s + (size_t)((hc * 16 + nt) * 64 + lane) * 8);
            acc2[0][nt] = __builtin_amdgcn_mfma_f32_16x16x32_bf16(h0, wv, acc2[0][nt], 0, 0, 0);
            acc2[1][nt] = __builtin_amdgcn_mfma_f32_16x16x32_bf16(h1, wv, acc2[1][nt], 0, 0, 0);
        }
    }

    // ---- epilogue: bias + relu + count-masked max over 32 rows, fp32 store
    #pragma unroll
    for (int nt = 0; nt < 16; ++nt) {
        const float bv = b2[nt * 16 + l15];
        float m = 0.f;                               // post-relu >= 0; self valid
        #pragma unroll
        for (int rg = 0; rg < 4; ++rg) {
            const int s0 = quad * 4 + rg;
            const float v0 = fmaxf(acc2[0][nt][rg] + bv, 0.f);
            const float v1 = fmaxf(acc2[1][nt][rg] + bv, 0.f);
            if (s0 < myc)      m = fmaxf(m, v0);
            if (16 + s0 < myc) m = fmaxf(m, v1);
        }
        m = fmaxf(m, __shfl_xor(m, 16, 64));
        m = fmaxf(m, __shfl_xor(m, 32, 64));
        if (lane < 16) out[(size_t)point * DOUTF + nt * 16 + l15] = m;
    }
}

extern "C" void kernel_launch(void* const* d_in, const int* in_sizes, int n_in,
                              void* d_out, int out_size, void* d_ws, size_t ws_size,
                              hipStream_t stream)
{
    // remap inputs by element-count fingerprint (R5 diag proved these sizes)
    const float *x = nullptr, *pos = nullptr, *W1 = nullptr, *W2 = nullptr;
    const float *b1 = nullptr, *b2 = nullptr;
    int nbias = 0;
    for (int i = 0; i < n_in && i < 16; ++i) {
        switch (in_sizes[i]) {
            case NPTS * DINF: x   = (const float*)d_in[i]; break;
            case NPTS * 3:    pos = (const float*)d_in[i]; break;
            case 131 * HID:   W1  = (const float*)d_in[i]; break;
            case HID * DOUTF: W2  = (const float*)d_in[i]; break;
            case 256:         if (nbias == 0) b1 = (const float*)d_in[i];
                              else            b2 = (const float*)d_in[i];
                              ++nbias; break;
            default: break;   // batch (unused; structurally i>>11)
        }
    }
    if (!x)   x   = (const float*)d_in[0];
    if (!pos) pos = (const float*)d_in[1];
    if (!W1)  W1  = (const float*)d_in[3];
    if (!b1)  b1  = (const float*)d_in[4];
    if (!W2)  W2  = (const float*)d_in[5];
    if (!b2)  b2  = (const float*)d_in[6];

    char* ws = (char*)d_ws;
    unsigned short* idx = (unsigned short*)(ws + 0);
    unsigned char*  cnt = (unsigned char*)(ws + 1048576);
    unsigned short* w1s = (unsigned short*)(ws + 1064960);
    unsigned short* w2s = (unsigned short*)(ws + 1146880);

    // fp32 output layout (R13-validated): out[N*256] | pos[N*3] | batch[N]
    float* out    = (float*)d_out;
    float* outpos = out + (size_t)NPTS * DOUTF;
    float* outbat = outpos + (size_t)NPTS * 3;

    hipLaunchKernelGGL(neigh_kernel, dim3(NPTS / 64), dim3(256), 0, stream, pos, idx, cnt);
    hipLaunchKernelGGL(prep_kernel,  dim3(52),        dim3(256), 0, stream, W1, W2, w1s, w2s);
    if (out_size >= NPTS * DOUTF + NPTS * 3 + NPTS) {
        hipLaunchKernelGGL(tail_kernel, dim3(256),    dim3(256), 0, stream, pos, outpos, outbat);
    }
    hipLaunchKernelGGL(sa_kernel,    dim3(NPTS / 4),  dim3(256), 0, stream,
                       x, pos, idx, cnt, w1s, w2s, b1, b2, out);
}

// Round 15
// 293.862 us; speedup vs baseline: 11.5433x; 1.0760x over previous
//
#include <hip/hip_runtime.h>
#include <hip/hip_bf16.h>

#define NPTS   16384
#define PPC    2048
#define DINF   128
#define KNB    32
#define HID    256
#define DOUTF  256

typedef __bf16 bf16x8 __attribute__((ext_vector_type(8)));
typedef float  f32x4  __attribute__((ext_vector_type(4)));

// ---- ws layout (bytes) ----
// [0,       1048576) : neighbor idx  ushort [NPTS][32]  (cloud-local j)
// [1048576, 1064960) : neighbor cnt  uchar  [NPTS]
// [1064960, 1146880) : W1 swizzled   bf16   [5][16][64][8]
// [1146880, 1277952) : W2 swizzled   bf16   [8][16][64][8]

static __device__ __forceinline__ unsigned short bf16bits(float f) {
    __hip_bfloat16 h = __float2bfloat16(f);
    return *reinterpret_cast<unsigned short*>(&h);
}

// ---------------------------------------------------------------------------
// Kernel 1: ball query (R13-validated semantics: descending-dot, no FMA,
// d2 = (n2i+n2j)-2*dot <= 0.04f, first-32-ascending-index).
// ---------------------------------------------------------------------------
__global__ __launch_bounds__(256) void neigh_kernel(
    const float* __restrict__ pos,
    unsigned short* __restrict__ idx,
    unsigned char* __restrict__ cnt)
{
    __shared__ __align__(16) float4 sp[PPC];
    __shared__ unsigned short lists[4][64][KNB];
    __shared__ unsigned char  scnt[4][64];

    const int tid = threadIdx.x;
    const int p0  = blockIdx.x * 64;
    const int cb  = (p0 / PPC) * PPC;

    for (int t = tid; t < PPC; t += 256) {
        const float x = pos[(size_t)(cb + t) * 3 + 0];
        const float y = pos[(size_t)(cb + t) * 3 + 1];
        const float z = pos[(size_t)(cb + t) * 3 + 2];
        const float n2 = __fadd_rn(__fadd_rn(__fmul_rn(x, x), __fmul_rn(y, y)), __fmul_rn(z, z));
        sp[t] = make_float4(x, y, z, n2);
    }
    __syncthreads();

    const int seg = tid >> 6;
    const int p   = tid & 63;
    const float4 pi = sp[p0 - cb + p];

    int c = 0;
    const int jb = seg * (PPC / 4);
    for (int jj = 0; jj < PPC / 4; ++jj) {
        const int j = jb + jj;
        const float4 pj = sp[j];
        const float dot = __fadd_rn(__fadd_rn(__fmul_rn(pi.z, pj.z), __fmul_rn(pi.y, pj.y)),
                                    __fmul_rn(pi.x, pj.x));   // descending (R13-validated)
        const float d2  = __fsub_rn(__fadd_rn(pi.w, pj.w), __fmul_rn(2.0f, dot));
        if (d2 <= 0.04f && c < KNB) { lists[seg][p][c] = (unsigned short)j; ++c; }
    }
    scnt[seg][p] = (unsigned char)c;
    __syncthreads();

    if (tid < 64) {
        const int point = p0 + tid;
        unsigned short* op = idx + (size_t)point * KNB;
        int k = 0;
        for (int s = 0; s < 4; ++s) {
            const int cc = scnt[s][tid];
            for (int r = 0; r < cc && k < KNB; ++r) op[k++] = lists[s][tid][r];
        }
        cnt[point] = (unsigned char)k;
        for (; k < KNB; ++k) op[k] = 0;
    }
}

// ---------------------------------------------------------------------------
// Kernel 2: swizzle fp32 W1/W2 -> bf16 MFMA B-fragment-major (unchanged).
// ---------------------------------------------------------------------------
__global__ __launch_bounds__(256) void prep_kernel(
    const float* __restrict__ W1, const float* __restrict__ W2,
    unsigned short* __restrict__ w1s, unsigned short* __restrict__ w2s)
{
    const int gid = blockIdx.x * 256 + threadIdx.x;
    if (gid < 5 * 1024) {
        const int ks = gid >> 10, rem = gid & 1023, nt = rem >> 6, lane = rem & 63;
        const int n  = nt * 16 + (lane & 15);
        const int k0 = ks * 32 + ((lane >> 4) * 8);
        unsigned int u[4];
        #pragma unroll
        for (int q = 0; q < 4; ++q) {
            const int ka = k0 + 2 * q, kb = ka + 1;
            const unsigned int lo = (ka < 131) ? (unsigned int)bf16bits(W1[(size_t)ka * HID + n]) : 0u;
            const unsigned int hi = (kb < 131) ? (unsigned int)bf16bits(W1[(size_t)kb * HID + n]) : 0u;
            u[q] = lo | (hi << 16);
        }
        reinterpret_cast<uint4*>(w1s)[gid] = make_uint4(u[0], u[1], u[2], u[3]);
    } else if (gid < 5 * 1024 + 8 * 1024) {
        const int t  = gid - 5 * 1024;
        const int ks = t >> 10, rem = t & 1023, nt = rem >> 6, lane = rem & 63;
        const int n  = nt * 16 + (lane & 15);
        const int k0 = ks * 32 + ((lane >> 4) * 8);
        unsigned int u[4];
        #pragma unroll
        for (int q = 0; q < 4; ++q) {
            const unsigned int lo = (unsigned int)bf16bits(W2[(size_t)(k0 + 2 * q) * DOUTF + n]);
            const unsigned int hi = (unsigned int)bf16bits(W2[(size_t)(k0 + 2 * q + 1) * DOUTF + n]);
            u[q] = lo | (hi << 16);
        }
        reinterpret_cast<uint4*>(w2s)[t] = make_uint4(u[0], u[1], u[2], u[3]);
    }
}

// ---------------------------------------------------------------------------
// Kernel 3: tuple tail, fp32.
// ---------------------------------------------------------------------------
__global__ __launch_bounds__(256) void tail_kernel(
    const float* __restrict__ pos,
    float* __restrict__ outpos,
    float* __restrict__ outbat)
{
    const int gid = blockIdx.x * 256 + threadIdx.x;
    if (gid < NPTS * 3) {
        outpos[gid] = pos[gid];
    } else {
        const int i = gid - NPTS * 3;
        if (i < NPTS) outbat[i] = (float)(i >> 11);
    }
}

// ---------------------------------------------------------------------------
// Kernel 4 (R15): block-wide 128-row GEMM, N-split waves.
// Block = 4 points = 128 gathered rows. Wave w owns output columns
// [w*64,(w+1)*64) for BOTH layers across ALL 128 rows:
//   layer1: 8 Mtiles x 4 Ntiles x 5 Ksteps; B-frags held in registers
//           (20 frags, disjoint per wave -> block loads w1s ONCE total).
//   h[128][256] bf16 staged in block LDS (stride 264 halves: 132 dwords
//   = 4 mod 32 -> min-cycle b128 reads). ONE barrier.
//   layer2: ks-outer, acc2[8][4] f32x4 (128 VGPR, 32 indep chains);
//           B-frags disjoint per wave -> block loads w2s ONCE.
// Fragment traffic: 52 KB/block vs R14's 832 KB (16x cut -> ~213 MB total).
// Barriers: 2 (was 17). LDS 106 KB -> 1 block/CU (4 waves).
// Accumulation order per output identical to R14 -> identical numerics.
// ---------------------------------------------------------------------------
#define MSG_STRIDE 160   // halves; 131 used + zero pad; conflict-min verified
#define HST        264   // halves; 256 used + 8 pad

__global__ __launch_bounds__(256, 1) void sa_kernel(
    const float* __restrict__ x,
    const float* __restrict__ pos,
    const unsigned short* __restrict__ idx,
    const unsigned char*  __restrict__ cnt,
    const unsigned short* __restrict__ w1s,
    const unsigned short* __restrict__ w2s,
    const float* __restrict__ b1,
    const float* __restrict__ b2,
    float* __restrict__ out)
{
    __shared__ __align__(16) unsigned short msg[128 * MSG_STRIDE];  // 40 KB
    __shared__ __align__(16) __bf16 hsh[128 * HST];                 // 66 KB

    const int tid   = threadIdx.x;
    const int pbase = blockIdx.x * 4;
    const int cb    = (pbase >> 11) << 11;          // all 4 points same cloud

    // ---- gather: msg[row][0..127]=bf16(x_j), [128..130]=rel, [131..159]=0
    #pragma unroll
    for (int it = 0; it < 8; ++it) {
        const int task  = it * 256 + tid;           // 0..2047
        const int r     = task >> 4;                // row 0..127
        const int sg    = task & 15;                // 8-float segment
        const int point = pbase + (r >> 5);
        const int slot  = r & 31;
        const int j     = idx[point * KNB + slot];
        const float* xf = x + (size_t)(cb + j) * DINF + sg * 8;
        const float4 pa = reinterpret_cast<const float4*>(xf)[0];
        const float4 pb = reinterpret_cast<const float4*>(xf)[1];
        uint4 v;
        v.x = (unsigned int)bf16bits(pa.x) | ((unsigned int)bf16bits(pa.y) << 16);
        v.y = (unsigned int)bf16bits(pa.z) | ((unsigned int)bf16bits(pa.w) << 16);
        v.z = (unsigned int)bf16bits(pb.x) | ((unsigned int)bf16bits(pb.y) << 16);
        v.w = (unsigned int)bf16bits(pb.z) | ((unsigned int)bf16bits(pb.w) << 16);
        *reinterpret_cast<uint4*>(&msg[r * MSG_STRIDE + sg * 8]) = v;
    }
    if (tid < 128) {
        const int r     = tid;
        const int point = pbase + (r >> 5);
        const int slot  = r & 31;
        const int j     = idx[point * KNB + slot];
        const float rx = pos[(size_t)(cb + j) * 3 + 0] - pos[(size_t)point * 3 + 0];
        const float ry = pos[(size_t)(cb + j) * 3 + 1] - pos[(size_t)point * 3 + 1];
        const float rz = pos[(size_t)(cb + j) * 3 + 2] - pos[(size_t)point * 3 + 2];
        uint4 vr;
        vr.x = (unsigned int)bf16bits(rx) | ((unsigned int)bf16bits(ry) << 16);
        vr.y = (unsigned int)bf16bits(rz);
        vr.z = 0u; vr.w = 0u;
        const uint4 z = make_uint4(0u, 0u, 0u, 0u);
        *reinterpret_cast<uint4*>(&msg[r * MSG_STRIDE + 128]) = vr;
        *reinterpret_cast<uint4*>(&msg[r * MSG_STRIDE + 136]) = z;
        *reinterpret_cast<uint4*>(&msg[r * MSG_STRIDE + 144]) = z;
        *reinterpret_cast<uint4*>(&msg[r * MSG_STRIDE + 152]) = z;
    }
    __syncthreads();

    const int w    = tid >> 6;                      // wave id: owns cols [w*64,w*64+64)
    const int lane = tid & 63;
    const int quad = lane >> 4;
    const int l15  = lane & 15;

    // ---- layer 1: cols (w*4+nt)*16+l15, all 8 Mtiles; B-frags in registers
    bf16x8 wf1[5][4];
    #pragma unroll
    for (int ks = 0; ks < 5; ++ks)
        #pragma unroll
        for (int nt = 0; nt < 4; ++nt)
            wf1[ks][nt] = *reinterpret_cast<const bf16x8*>(
                w1s + (size_t)((ks * 16 + (w * 4 + nt)) * 64 + lane) * 8);
    float bb1[4];
    #pragma unroll
    for (int nt = 0; nt < 4; ++nt) bb1[nt] = b1[(w * 4 + nt) * 16 + l15];

    const f32x4 fz = {0.f, 0.f, 0.f, 0.f};
    #pragma unroll
    for (int mt = 0; mt < 8; ++mt) {
        f32x4 a1[4] = {fz, fz, fz, fz};
        #pragma unroll
        for (int ks = 0; ks < 5; ++ks) {
            const bf16x8 av = *reinterpret_cast<const bf16x8*>(
                msg + (mt * 16 + l15) * MSG_STRIDE + ks * 32 + quad * 8);
            #pragma unroll
            for (int nt = 0; nt < 4; ++nt)
                a1[nt] = __builtin_amdgcn_mfma_f32_16x16x32_bf16(av, wf1[ks][nt], a1[nt], 0, 0, 0);
        }
        // bias+relu+bf16 -> h (C layout: row = mt*16+quad*4+rg, col = (w*4+nt)*16+l15)
        #pragma unroll
        for (int nt = 0; nt < 4; ++nt) {
            const int col = (w * 4 + nt) * 16 + l15;
            #pragma unroll
            for (int rg = 0; rg < 4; ++rg)
                hsh[(mt * 16 + quad * 4 + rg) * HST + col] = (__bf16)fmaxf(a1[nt][rg] + bb1[nt], 0.f);
        }
    }
    __syncthreads();   // h writes -> h reads (only mid-kernel barrier)

    // ---- layer 2: ks-outer, acc2[8][4] (32 independent chains)
    f32x4 acc2[8][4];
    #pragma unroll
    for (int mt = 0; mt < 8; ++mt)
        #pragma unroll
        for (int nt = 0; nt < 4; ++nt) acc2[mt][nt] = fz;

    #pragma unroll
    for (int ks = 0; ks < 8; ++ks) {
        bf16x8 wf2[4];
        #pragma unroll
        for (int nt = 0; nt < 4; ++nt)
            wf2[nt] = *reinterpret_cast<const bf16x8*>(
                w2s + (size_t)((ks * 16 + (w * 4 + nt)) * 64 + lane) * 8);
        #pragma unroll
        for (int mt = 0; mt < 8; ++mt) {
            const bf16x8 hv = *reinterpret_cast<const bf16x8*>(
                hsh + (mt * 16 + l15) * HST + ks * 32 + quad * 8);
            #pragma unroll
            for (int nt = 0; nt < 4; ++nt)
                acc2[mt][nt] = __builtin_amdgcn_mfma_f32_16x16x32_bf16(hv, wf2[nt], acc2[mt][nt], 0, 0, 0);
        }
    }

    // ---- epilogue: bias + relu + count-masked max per point, fp32 store
    int myc[4];
    #pragma unroll
    for (int p = 0; p < 4; ++p) {
        int c = cnt[pbase + p];
        myc[p] = (c > KNB) ? KNB : c;
    }
    #pragma unroll
    for (int nt = 0; nt < 4; ++nt) {
        const int col = (w * 4 + nt) * 16 + l15;
        const float bv = b2[col];
        #pragma unroll
        for (int p = 0; p < 4; ++p) {
            float m = 0.f;                           // post-relu >= 0; self valid
            #pragma unroll
            for (int hh = 0; hh < 2; ++hh) {
                const int mt = 2 * p + hh;
                #pragma unroll
                for (int rg = 0; rg < 4; ++rg) {
                    const int slot = hh * 16 + quad * 4 + rg;
                    const float v = fmaxf(acc2[mt][nt][rg] + bv, 0.f);
                    if (slot < myc[p]) m = fmaxf(m, v);
                }
            }
            m = fmaxf(m, __shfl_xor(m, 16, 64));
            m = fmaxf(m, __shfl_xor(m, 32, 64));
            if (lane < 16) out[(size_t)(pbase + p) * DOUTF + col] = m;
        }
    }
}

extern "C" void kernel_launch(void* const* d_in, const int* in_sizes, int n_in,
                              void* d_out, int out_size, void* d_ws, size_t ws_size,
                              hipStream_t stream)
{
    const float *x = nullptr, *pos = nullptr, *W1 = nullptr, *W2 = nullptr;
    const float *b1 = nullptr, *b2 = nullptr;
    int nbias = 0;
    for (int i = 0; i < n_in && i < 16; ++i) {
        switch (in_sizes[i]) {
            case NPTS * DINF: x   = (const float*)d_in[i]; break;
            case NPTS * 3:    pos = (const float*)d_in[i]; break;
            case 131 * HID:   W1  = (const float*)d_in[i]; break;
            case HID * DOUTF: W2  = (const float*)d_in[i]; break;
            case 256:         if (nbias == 0) b1 = (const float*)d_in[i];
                              else            b2 = (const float*)d_in[i];
                              ++nbias; break;
            default: break;   // batch (unused; structurally i>>11)
        }
    }
    if (!x)   x   = (const float*)d_in[0];
    if (!pos) pos = (const float*)d_in[1];
    if (!W1)  W1  = (const float*)d_in[3];
    if (!b1)  b1  = (const float*)d_in[4];
    if (!W2)  W2  = (const float*)d_in[5];
    if (!b2)  b2  = (const float*)d_in[6];

    char* ws = (char*)d_ws;
    unsigned short* idx = (unsigned short*)(ws + 0);
    unsigned char*  cnt = (unsigned char*)(ws + 1048576);
    unsigned short* w1s = (unsigned short*)(ws + 1064960);
    unsigned short* w2s = (unsigned short*)(ws + 1146880);

    float* out    = (float*)d_out;
    float* outpos = out + (size_t)NPTS * DOUTF;
    float* outbat = outpos + (size_t)NPTS * 3;

    hipLaunchKernelGGL(neigh_kernel, dim3(NPTS / 64), dim3(256), 0, stream, pos, idx, cnt);
    hipLaunchKernelGGL(prep_kernel,  dim3(52),        dim3(256), 0, stream, W1, W2, w1s, w2s);
    if (out_size >= NPTS * DOUTF + NPTS * 3 + NPTS) {
        hipLaunchKernelGGL(tail_kernel, dim3(256),    dim3(256), 0, stream, pos, outpos, outbat);
    }
    hipLaunchKernelGGL(sa_kernel,    dim3(NPTS / 4),  dim3(256), 0, stream,
                       x, pos, idx, cnt, w1s, w2s, b1, b2, out);
}